// Round 1
// baseline (1332.140 us; speedup 1.0000x reference)
//
#include <hip/hip_runtime.h>
#include <math.h>

#define N_LOCS 16384
#define START 4096
#define NB 12288
#define NMAT 96
#define KDIM 60

__global__ void minnz_kernel(const float* __restrict__ scales, unsigned* __restrict__ ws) {
    int idx = blockIdx.x * 256 + threadIdx.x;
    if (idx < NB) {
        float v = scales[START + idx];
        if (v != 0.0f) atomicMin(ws, __float_as_uint(v));
    }
}

__launch_bounds__(256)
__global__ void fused_kernel(const float* __restrict__ kp,
                             const float* __restrict__ aug,
                             const float* __restrict__ scales,
                             const float* __restrict__ nug,
                             const unsigned* __restrict__ ws,
                             float* __restrict__ out)
{
    const int b = blockIdx.x;
    const int t = threadIdx.x;
    const int ti = t >> 4, tj = t & 15;

    float* outG = out;                                   // [NB][96][96]
    float* outL = out + (size_t)NB * NMAT * NMAT;        // [NB][96][96]
    float* outN = out + 2 * (size_t)NB * NMAT * NMAT;    // [NB]

    if (t == 0) outN[b] = nug[b];

    const size_t gbase = (size_t)b * (NMAT * NMAT);

    if (b == 0) {
        // reference: g[0] = I, chol(I) = I
        #pragma unroll
        for (int u = 0; u < 6; ++u) {
            int i = ti * 6 + u;
            #pragma unroll
            for (int v = 0; v < 6; ++v) {
                int j = tj * 6 + v;
                float e = (i == j) ? 1.0f : 0.0f;
                outG[gbase + (size_t)i * NMAT + j] = e;
                outL[gbase + (size_t)i * NMAT + j] = e;
            }
        }
        return;
    }

    __shared__ float sx[NMAT * 61];      // x tile, stride 61 (conflict-free)
    __shared__ float sdiag[NMAT];        // gram diagonal
    __shared__ float spanel[NMAT * 6];   // cholesky panel broadcast
    __shared__ float sL6[36];            // diag-block factor
    __shared__ float srinv[6];           // reciprocal diag of L6

    // ---- scalar parameters (r=1, R=2 per setup_inputs) ----
    const float kp1 = kp[1], kp3 = kp[3], kp5 = kp[5], kp7 = kp[7];
    const float kp8 = kp[8], kp9 = kp[9], kp11 = kp[11];
    float sc = scales[START + b];
    if (sc == 0.0f) sc = __uint_as_float(ws[0]) * 0.5f;
    const float sigma   = __expf(kp1 + kp3 * __logf(sc));
    const float sigma2  = sigma * sigma;
    const float inv_ls2 = 1.0f / (3.0f * __expf(2.0f * kp11));  // ls^2 = 3*exp(2*kp11)
    const float inv_nug = 1.0f / nug[b];

    // ---- per-lane scaling coefficient (lane owns column c of x) ----
    const int c = t & 63;
    float myscale = 0.0f;
    if (c < 60) {
        float kf = (c < 30) ? (float)(c + 1) : (float)(c - 29);
        float th = (c < 30) ? kp5 : kp8;
        float de = (c < 30) ? kp7 : kp9;
        myscale = __expf(th - 0.5f * __expf(de) * kf);
    }

    // ---- stage x into LDS: x[i][c] = aug[i, START+b, 1+c] * scaling[c], NaN->0 ----
    {
        const int rbase = t >> 6;  // 0..3 (4 rows per iteration)
        if (c < 60) {
            const size_t rowstride = (size_t)N_LOCS * 61;
            const size_t base = (size_t)(START + b) * 61 + 1 + c;
            for (int it = 0; it < 24; ++it) {
                int i = it * 4 + rbase;
                float v = aug[base + (size_t)i * rowstride];
                v = (v != v) ? 0.0f : v;
                sx[i * 61 + c] = v * myscale;
            }
        }
    }
    __syncthreads();

    // ---- gram: acc[u][v] = sum_k x[ti*6+u][k] * x[tj*6+v][k] ----
    float acc[6][6];
    #pragma unroll
    for (int u = 0; u < 6; ++u)
        #pragma unroll
        for (int v = 0; v < 6; ++v) acc[u][v] = 0.0f;

    for (int k = 0; k < KDIM; ++k) {
        float av[6], bv[6];
        #pragma unroll
        for (int u = 0; u < 6; ++u) av[u] = sx[(ti * 6 + u) * 61 + k];
        #pragma unroll
        for (int v = 0; v < 6; ++v) bv[v] = sx[(tj * 6 + v) * 61 + k];
        #pragma unroll
        for (int u = 0; u < 6; ++u)
            #pragma unroll
            for (int v = 0; v < 6; ++v) acc[u][v] = fmaf(av[u], bv[v], acc[u][v]);
    }

    if (ti == tj) {
        #pragma unroll
        for (int u = 0; u < 6; ++u) sdiag[ti * 6 + u] = acc[u][u];
    }
    __syncthreads();

    float di[6], dj[6];
    #pragma unroll
    for (int u = 0; u < 6; ++u) di[u] = sdiag[ti * 6 + u];
    #pragma unroll
    for (int v = 0; v < 6; ++v) dj[v] = sdiag[tj * 6 + v];

    // ---- transform to g = (linear + sigma^2*(1+c)exp(-c))/nug + I ----
    #pragma unroll
    for (int u = 0; u < 6; ++u) {
        int i = ti * 6 + u;
        #pragma unroll
        for (int v = 0; v < 6; ++v) {
            int j = tj * 6 + v;
            float lin = acc[u][v];
            float d2 = (di[u] + dj[v] - 2.0f * lin) * inv_ls2;
            d2 = fmaxf(d2, 0.0f);
            float cc = sqrtf(3.0f * d2);
            float nl = (1.0f + cc) * __expf(-cc);
            acc[u][v] = fmaf(sigma2, nl, lin) * inv_nug + ((i == j) ? 1.0f : 0.0f);
        }
    }

    // ---- write g (float2 stores, 8B-aligned since tj*6+v even) ----
    #pragma unroll
    for (int u = 0; u < 6; ++u) {
        size_t row = gbase + (size_t)(ti * 6 + u) * NMAT + tj * 6;
        #pragma unroll
        for (int v = 0; v < 6; v += 2) {
            *(float2*)&outG[row + v] = make_float2(acc[u][v], acc[u][v + 1]);
        }
    }

    // ---- blocked cholesky (block=6) on register-distributed matrix ----
    for (int jb = 0; jb < 16; ++jb) {
        if (ti == jb && tj == jb) {
            // factor own 6x6 lower
            #pragma unroll
            for (int c2 = 0; c2 < 6; ++c2) {
                float s = acc[c2][c2];
                #pragma unroll
                for (int m = 0; m < 6; ++m) if (m < c2) s -= acc[c2][m] * acc[c2][m];
                float l = sqrtf(s);
                acc[c2][c2] = l;
                float rinv = 1.0f / l;
                srinv[c2] = rinv;
                #pragma unroll
                for (int rr = 0; rr < 6; ++rr) if (rr > c2) {
                    float s2 = acc[rr][c2];
                    #pragma unroll
                    for (int m = 0; m < 6; ++m) if (m < c2) s2 -= acc[rr][m] * acc[c2][m];
                    acc[rr][c2] = s2 * rinv;
                }
                #pragma unroll
                for (int m = 0; m < 6; ++m) sL6[c2 * 6 + m] = acc[c2][m];
            }
        }
        __syncthreads();
        if (tj == jb && ti > jb) {
            // panel solve: row u: l[c2] = (a[c2] - sum_{m<c2} l[m]*L6[c2][m]) / L6[c2][c2]
            #pragma unroll
            for (int u = 0; u < 6; ++u) {
                #pragma unroll
                for (int c2 = 0; c2 < 6; ++c2) {
                    float s = acc[u][c2];
                    #pragma unroll
                    for (int m = 0; m < 6; ++m) if (m < c2) s -= acc[u][m] * sL6[c2 * 6 + m];
                    acc[u][c2] = s * srinv[c2];
                }
                #pragma unroll
                for (int c2 = 0; c2 < 6; ++c2) spanel[(ti * 6 + u) * 6 + c2] = acc[u][c2];
            }
        }
        __syncthreads();
        if (tj > jb && ti >= tj) {
            // trailing rank-6 update: acc -= P(ti) * P(tj)^T
            float pu[6][6], pv[6][6];
            #pragma unroll
            for (int u = 0; u < 6; ++u)
                #pragma unroll
                for (int m = 0; m < 6; ++m) pu[u][m] = spanel[(ti * 6 + u) * 6 + m];
            #pragma unroll
            for (int v = 0; v < 6; ++v)
                #pragma unroll
                for (int m = 0; m < 6; ++m) pv[v][m] = spanel[(tj * 6 + v) * 6 + m];
            #pragma unroll
            for (int u = 0; u < 6; ++u)
                #pragma unroll
                for (int v = 0; v < 6; ++v) {
                    float s = acc[u][v];
                    #pragma unroll
                    for (int m = 0; m < 6; ++m) s = fmaf(-pu[u][m], pv[v][m], s);
                    acc[u][v] = s;
                }
        }
    }

    // ---- write chol (upper tiles = 0, diag tiles upper-zeroed) ----
    #pragma unroll
    for (int u = 0; u < 6; ++u) {
        int i = ti * 6 + u;
        size_t row = gbase + (size_t)i * NMAT + tj * 6;
        #pragma unroll
        for (int v = 0; v < 6; v += 2) {
            int j0 = tj * 6 + v;
            float a0 = acc[u][v], a1 = acc[u][v + 1];
            if (ti < tj) { a0 = 0.0f; a1 = 0.0f; }
            else if (ti == tj) {
                if (j0 > i)     a0 = 0.0f;
                if (j0 + 1 > i) a1 = 0.0f;
            }
            *(float2*)&outL[row + v] = make_float2(a0, a1);
        }
    }
}

extern "C" void kernel_launch(void* const* d_in, const int* in_sizes, int n_in,
                              void* d_out, int out_size, void* d_ws, size_t ws_size,
                              hipStream_t stream) {
    const float* kp     = (const float*)d_in[0];
    const float* aug    = (const float*)d_in[1];
    const float* scales = (const float*)d_in[2];
    const float* nug    = (const float*)d_in[3];
    float* out = (float*)d_out;
    unsigned* ws = (unsigned*)d_ws;

    // sentinel = 0xFFFFFFFF (max uint) for the nonzero-min reduction
    hipMemsetAsync(ws, 0xFF, 4, stream);
    minnz_kernel<<<(NB + 255) / 256, 256, 0, stream>>>(scales, ws);
    fused_kernel<<<NB, 256, 0, stream>>>(kp, aug, scales, nug, ws, out);
}